// Round 16
// baseline (156.863 us; speedup 1.0000x reference)
//
#include <hip/hip_runtime.h>
#include <hip/hip_fp16.h>
#include <math.h>

static constexpr int N_NODES = 50000;
static constexpr int E_EDGES = 800000;
static constexpr int IN_F = 64;
static constexpr int H_F = 128;
static constexpr int K_C = 16;
static constexpr int BUCK_SHIFT = 7;                          // 128 nodes/bucket
static constexpr int NBUCK = (N_NODES + 127) >> BUCK_SHIFT;   // 391
static constexpr int CHUNK_E = 4096;
static constexpr int NCHUNK = (E_EDGES + CHUNK_E - 1) / CHUNK_E; // 196
static constexpr int BUCK_CAP = 4096;
static constexpr int PREP_B = 3221;                           // prep blocks (824576 items)

typedef _Float16 h4 __attribute__((ext_vector_type(4)));
typedef _Float16 h8 __attribute__((ext_vector_type(8)));
typedef float f4 __attribute__((ext_vector_type(4)));

__device__ __forceinline__ void unpack(unsigned int e, int& s, float& w) {
  s = (int)(e & 0xffffu);
  w = __half2float(__ushort_as_half((unsigned short)(e >> 16)));
}

// ---------------- fused prep (f2h + W transposes) + bucket histogram ----------------
__global__ __launch_bounds__(256) void prep_hist(
    const float* __restrict__ x, __half* __restrict__ xh,
    const float* __restrict__ W1, __half* __restrict__ WT1,
    const float* __restrict__ W2, __half* __restrict__ WT2,
    const int* __restrict__ dst, int* __restrict__ bcount) {
  __shared__ int lh[NBUCK];
  if (blockIdx.x < PREP_B) {
    const int i = blockIdx.x * 256 + threadIdx.x;
    const int n4 = N_NODES * IN_F / 4;           // 800000
    if (i < n4) {
      float4 v = ((const float4*)x)[i];
      __half2* o = (__half2*)xh + (size_t)i * 2;
      o[0] = __floats2half2_rn(v.x, v.y);
      o[1] = __floats2half2_rn(v.z, v.w);
    }
    const int j = i - n4;
    if (j >= 0 && j < IN_F * 128) {
      const int k = j >> 7, col = j & 127;
      unsigned boff = (unsigned)((col * IN_F + k) * 2) ^ (unsigned)((col & 7) << 4);
      *(__half*)((char*)WT1 + boff) = __float2half_rn(W1[j]);
    }
    const int k2 = j - IN_F * 128;
    if (k2 >= 0 && k2 < H_F * 128) {
      const int k = k2 >> 7, col = k2 & 127;
      unsigned boff = (unsigned)((col * H_F + k) * 2) ^ (unsigned)((col & 7) << 4);
      *(__half*)((char*)WT2 + boff) = __float2half_rn(W2[k2]);
    }
  } else {
    const int cb = blockIdx.x - PREP_B;
    for (int i = threadIdx.x; i < NBUCK; i += 256) lh[i] = 0;
    __syncthreads();
    const int e0 = cb * CHUNK_E;
    const int cnt = min(CHUNK_E, E_EDGES - e0);
    for (int i = threadIdx.x; i < cnt; i += 256)
      atomicAdd(&lh[dst[e0 + i] >> BUCK_SHIFT], 1);
    __syncthreads();
    for (int i = threadIdx.x; i < NBUCK; i += 256)
      if (lh[i]) atomicAdd(&bcount[i], lh[i]);
  }
}

// ---------------- bin_pass: chunk -> bucket-sorted runs into inter ----------------
// Also computes global bucket bases from bcount in-block (scan) and writes them
// (idempotently) to bbase_g. Reservations use zero-initialized bcursor.
__global__ __launch_bounds__(256) void bin_pass(
    const int* __restrict__ src, const int* __restrict__ dst,
    const float* __restrict__ w, const int* __restrict__ bcount,
    int* __restrict__ bcursor, int* __restrict__ bbase_g,
    int2* __restrict__ inter) {
  __shared__ int lhist[NBUCK];
  __shared__ int lstart[NBUCK];
  __shared__ int bbase_s[NBUCK];
  __shared__ int2 stage[CHUNK_E];  // 32 KB
  const int e0 = blockIdx.x * CHUNK_E;
  const int cnt = min(CHUNK_E, E_EDGES - e0);

  for (int i = threadIdx.x; i < NBUCK; i += 256) lhist[i] = 0;
  __syncthreads();
  for (int i = threadIdx.x; i < cnt; i += 256)
    atomicAdd(&lhist[dst[e0 + i] >> BUCK_SHIFT], 1);
  __syncthreads();

  if (threadIdx.x < 64) {
    const int lane = threadIdx.x;
    int carry = 0, carryG = 0;
    for (int base = 0; base < NBUCK; base += 64) {
      const int idx = base + lane;
      const int v  = (idx < NBUCK) ? lhist[idx] : 0;
      const int vg = (idx < NBUCK) ? bcount[idx] : 0;
      int inc = v, incG = vg;
#pragma unroll
      for (int d = 1; d < 64; d <<= 1) {
        int u  = __shfl_up(inc, d);
        int uG = __shfl_up(incG, d);
        if (lane >= d) { inc += u; incG += uG; }
      }
      if (idx < NBUCK) {
        lstart[idx] = carry + inc - v;
        const int gb = carryG + incG - vg;
        bbase_s[idx] = gb;
        bbase_g[idx] = gb;            // idempotent across blocks
      }
      carry  += __shfl(inc, 63);
      carryG += __shfl(incG, 63);
    }
    if (lane == 0) bbase_g[NBUCK] = E_EDGES;
  }
  __syncthreads();

  for (int b = threadIdx.x; b < NBUCK; b += 256) {
    const int c = lhist[b];
    bbase_s[b] += (c > 0) ? atomicAdd(&bcursor[b], c) : 0;
    lhist[b] = lstart[b];
  }
  __syncthreads();

  for (int i = threadIdx.x; i < cnt; i += 256) {
    const int d = dst[e0 + i];
    const int b = d >> BUCK_SHIFT;
    const int pos = atomicAdd(&lhist[b], 1);
    const unsigned short wb = __half_as_ushort(__float2half_rn(w[e0 + i]));
    stage[pos] = make_int2(src[e0 + i] | ((d & 127) << 16),
                           (int)wb | (b << 16));
  }
  __syncthreads();

  for (int i = threadIdx.x; i < cnt; i += 256) {
    const int2 en = stage[i];
    const int b = (en.y >> 16) & 0x1ff;
    inter[bbase_s[b] + (i - lstart[b])] = en;
  }
}

// ---------------- sortoff: per-bucket fine sort + write node-level off ----------------
__global__ __launch_bounds__(256) void sortoff_pass(
    const int2* __restrict__ inter, const int* __restrict__ bbase,
    unsigned int* __restrict__ csr, int* __restrict__ off) {
  __shared__ int lhist[128];
  __shared__ int lstart[128];
  __shared__ unsigned int outbuf[BUCK_CAP];  // 16 KB
  const int b = blockIdx.x;
  const int n0 = b << BUCK_SHIFT;
  const int r0 = bbase[b];
  const int r1 = bbase[b + 1];
  const int cnt = r1 - r0;

  if (threadIdx.x < 128) lhist[threadIdx.x] = 0;
  __syncthreads();
  for (int i = threadIdx.x; i < cnt; i += 256)
    atomicAdd(&lhist[(inter[r0 + i].x >> 16) & 127], 1);
  __syncthreads();

  if (threadIdx.x < 64) {
    const int lane = threadIdx.x;
    int carry = 0;
#pragma unroll
    for (int base = 0; base < 128; base += 64) {
      const int v = lhist[base + lane];
      int inc = v;
#pragma unroll
      for (int d = 1; d < 64; d <<= 1) {
        int u = __shfl_up(inc, d);
        if (lane >= d) inc += u;
      }
      lstart[base + lane] = carry + inc - v;
      carry += __shfl(inc, 63);
    }
  }
  __syncthreads();

  if (threadIdx.x < 128) {
    const int nn = n0 + threadIdx.x;
    if (nn < N_NODES) off[nn] = r0 + lstart[threadIdx.x];
    lhist[threadIdx.x] = lstart[threadIdx.x];
  }
  if (b == NBUCK - 1 && threadIdx.x == 0) off[N_NODES] = E_EDGES;
  __syncthreads();

  for (int i = threadIdx.x; i < cnt; i += 256) {
    const int2 en = inter[r0 + i];
    const int dlo = (en.x >> 16) & 127;
    const int pos = atomicAdd(&lhist[dlo], 1);
    outbuf[pos] = (unsigned int)(en.x & 0xffff) |
                  ((unsigned int)(en.y & 0xffff) << 16);
  }
  __syncthreads();
  for (int i = threadIdx.x; i < cnt; i += 256) csr[r0 + i] = outbuf[i];
}

// ---------------- gather_x: wave/node, 4 edge-slots x 16 feat-lanes; masked-16 tail ----------------
__global__ __launch_bounds__(256) void gather_x(
    const __half* __restrict__ t, const int* __restrict__ off,
    const unsigned int* __restrict__ csr, __half* __restrict__ outb) {
  const int node = blockIdx.x * 4 + (threadIdx.x >> 6);
  const int l = threadIdx.x & 63;
  const int g = l >> 4;                 // edge slot 0..3
  const int f0 = (l & 15) * 4;          // 4 feats per lane
  const int p0 = off[node], p1 = off[node + 1];
  f4 a0 = {0.f, 0.f, 0.f, 0.f}, a1 = {0.f, 0.f, 0.f, 0.f};
  int p = p0;
  for (; p + 16 <= p1; p += 16) {
    int s[4]; float w[4]; h4 v[4];
#pragma unroll
    for (int u = 0; u < 4; ++u) unpack(csr[p + 4 * u + g], s[u], w[u]);
#pragma unroll
    for (int u = 0; u < 4; ++u) v[u] = *(const h4*)(t + (size_t)s[u] * IN_F + f0);
#pragma unroll
    for (int u = 0; u < 4; ++u) {
      f4& a = (u & 1) ? a1 : a0;
      a.x = fmaf((float)v[u].x, w[u], a.x); a.y = fmaf((float)v[u].y, w[u], a.y);
      a.z = fmaf((float)v[u].z, w[u], a.z); a.w = fmaf((float)v[u].w, w[u], a.w);
    }
  }
  if (p < p1) {   // masked 16-wide tail
    int s[4]; float w[4]; h4 v[4];
#pragma unroll
    for (int u = 0; u < 4; ++u) {
      const int idx = p + 4 * u + g;
      unpack(csr[min(idx, p1 - 1)], s[u], w[u]);
      if (idx >= p1) w[u] = 0.f;
    }
#pragma unroll
    for (int u = 0; u < 4; ++u) v[u] = *(const h4*)(t + (size_t)s[u] * IN_F + f0);
#pragma unroll
    for (int u = 0; u < 4; ++u) {
      f4& a = (u & 1) ? a1 : a0;
      a.x = fmaf((float)v[u].x, w[u], a.x); a.y = fmaf((float)v[u].y, w[u], a.y);
      a.z = fmaf((float)v[u].z, w[u], a.z); a.w = fmaf((float)v[u].w, w[u], a.w);
    }
  }
  a0.x += a1.x; a0.y += a1.y; a0.z += a1.z; a0.w += a1.w;
  a0.x += __shfl_xor(a0.x, 16); a0.y += __shfl_xor(a0.y, 16);
  a0.z += __shfl_xor(a0.z, 16); a0.w += __shfl_xor(a0.w, 16);
  a0.x += __shfl_xor(a0.x, 32); a0.y += __shfl_xor(a0.y, 32);
  a0.z += __shfl_xor(a0.z, 32); a0.w += __shfl_xor(a0.w, 32);
  if (l < 16) {
    h4 o;
    o.x = (_Float16)a0.x; o.y = (_Float16)a0.y;
    o.z = (_Float16)a0.z; o.w = (_Float16)a0.w;
    *(h4*)(outb + (size_t)node * IN_F + f0) = o;
  }
}

// ---------------- MFMA dense transform ----------------
template<int K, bool BIAS_RELU>
__global__ __launch_bounds__(256) void gemm_mfma(
    const __half* __restrict__ A, const __half* __restrict__ WT,
    const float* __restrict__ bias, __half* __restrict__ out, int n) {
  __shared__ _Float16 Wl[128 * K];
  for (int t = threadIdx.x; t < 128 * K / 8; t += 256)
    ((uint4*)Wl)[t] = ((const uint4*)WT)[t];
  __syncthreads();

  const int wv = threadIdx.x >> 6;
  const int l = threadIdx.x & 63;
  const int row = l & 15, kg = l >> 4;
  const int r0 = blockIdx.x * 64 + wv * 16;
  const int ar = min(r0 + row, n - 1);

  h8 af[K / 32];
#pragma unroll
  for (int ks = 0; ks < K / 32; ++ks)
    af[ks] = *(const h8*)(A + (size_t)ar * K + ks * 32 + kg * 8);

  const unsigned swz = (unsigned)((row & 7) << 4);
#pragma unroll
  for (int c = 0; c < 8; ++c) {
    const int col = c * 16 + row;
    f4 acc = {0.f, 0.f, 0.f, 0.f};
#pragma unroll
    for (int ks = 0; ks < K / 32; ++ks) {
      const unsigned boff = ((unsigned)((col * K + ks * 32 + kg * 8) * 2)) ^ swz;
      const h8 bf = *(const h8*)((const char*)Wl + boff);
      acc = __builtin_amdgcn_mfma_f32_16x16x32_f16(af[ks], bf, acc, 0, 0, 0);
    }
    const float bb = BIAS_RELU ? bias[col] : 0.f;
#pragma unroll
    for (int q = 0; q < 4; ++q) {
      const int rr = r0 + kg * 4 + q;
      if (rr < n) {
        float v = acc[q];
        if (BIAS_RELU) v = fmaxf(v + bb, 0.f);
        out[(size_t)rr * H_F + col] = __float2half_rn(v);
      }
    }
  }
}

// ---------------- gather_h: wave/node, full-row lanes, 16-wide + masked-16 tail (R14) ----------------
__global__ __launch_bounds__(256) void gather_h(
    const __half* __restrict__ t, const int* __restrict__ off,
    const unsigned int* __restrict__ csr, __half* __restrict__ outb) {
  const int node = blockIdx.x * 4 + (threadIdx.x >> 6);
  const int lane = threadIdx.x & 63;
  const __half2* __restrict__ tb = (const __half2*)t;
  const int p0 = off[node], p1 = off[node + 1];
  float2 a[4];
#pragma unroll
  for (int i = 0; i < 4; ++i) a[i] = make_float2(0.f, 0.f);
  int p = p0;
  for (; p + 16 <= p1; p += 16) {
    int s[16]; float w[16]; __half2 hv[16];
#pragma unroll
    for (int i = 0; i < 16; ++i) unpack(csr[p + i], s[i], w[i]);
#pragma unroll
    for (int i = 0; i < 16; ++i) hv[i] = tb[(size_t)s[i] * 64 + lane];
#pragma unroll
    for (int i = 0; i < 16; ++i) {
      const float2 f = __half22float2(hv[i]);
      a[i & 3].x = fmaf(f.x, w[i], a[i & 3].x);
      a[i & 3].y = fmaf(f.y, w[i], a[i & 3].y);
    }
  }
  if (p < p1) {   // masked 16-wide tail
    int s[16]; float w[16]; __half2 hv[16];
#pragma unroll
    for (int i = 0; i < 16; ++i) {
      unpack(csr[min(p + i, p1 - 1)], s[i], w[i]);
      if (p + i >= p1) w[i] = 0.f;
    }
#pragma unroll
    for (int i = 0; i < 16; ++i) hv[i] = tb[(size_t)s[i] * 64 + lane];
#pragma unroll
    for (int i = 0; i < 16; ++i) {
      const float2 f = __half22float2(hv[i]);
      a[i & 3].x = fmaf(f.x, w[i], a[i & 3].x);
      a[i & 3].y = fmaf(f.y, w[i], a[i & 3].y);
    }
  }
  const float2 s2 = make_float2((a[0].x + a[1].x) + (a[2].x + a[3].x),
                                (a[0].y + a[1].y) + (a[2].y + a[3].y));
  ((__half2*)outb)[(size_t)node * 64 + lane] = __float22half2_rn(s2);
}

// ---------------- head (+ fused loss via last-block counter) ----------------
__global__ __launch_bounds__(256) void head_kernel(
    const __half* __restrict__ h2raw, const float* __restrict__ b2,
    const float* __restrict__ Wm, const float* __restrict__ bm,
    float* __restrict__ sm_out, float* __restrict__ diag,
    unsigned int* __restrict__ ctr, float* __restrict__ loss_out, int n) {
  __shared__ float Wl[H_F * K_C];   // 8 KB, [k][c]
  __shared__ float b2l[H_F];
  __shared__ float part[K_C];
  __shared__ int lastf;
  for (int t = threadIdx.x; t < H_F * K_C; t += 256) Wl[t] = Wm[t];
  if (threadIdx.x < H_F) b2l[threadIdx.x] = b2[threadIdx.x];
  if (threadIdx.x < K_C) part[threadIdx.x] = 0.f;
  __syncthreads();

  const int node = blockIdx.x * 256 + threadIdx.x;
  const int lane = threadIdx.x & 63;
  float acc[K_C];
#pragma unroll
  for (int c = 0; c < K_C; ++c) acc[c] = bm[c];

  if (node < n) {
    const __half2* __restrict__ hrow = (const __half2*)(h2raw + (size_t)node * H_F);
#pragma unroll 4
    for (int k2 = 0; k2 < H_F / 2; ++k2) {
      const float2 hv = __half22float2(hrow[k2]);
      const float h0 = fmaxf(hv.x + b2l[2 * k2], 0.f);
      const float h1 = fmaxf(hv.y + b2l[2 * k2 + 1], 0.f);
      const float4* __restrict__ w0 = (const float4*)(Wl + (2 * k2) * K_C);      // uniform
      const float4* __restrict__ w1 = (const float4*)(Wl + (2 * k2 + 1) * K_C);  // uniform
#pragma unroll
      for (int qq = 0; qq < 4; ++qq) {
        const float4 aa = w0[qq], bb = w1[qq];
        acc[4 * qq + 0] = fmaf(h0, aa.x, acc[4 * qq + 0]);
        acc[4 * qq + 1] = fmaf(h0, aa.y, acc[4 * qq + 1]);
        acc[4 * qq + 2] = fmaf(h0, aa.z, acc[4 * qq + 2]);
        acc[4 * qq + 3] = fmaf(h0, aa.w, acc[4 * qq + 3]);
        acc[4 * qq + 0] = fmaf(h1, bb.x, acc[4 * qq + 0]);
        acc[4 * qq + 1] = fmaf(h1, bb.y, acc[4 * qq + 1]);
        acc[4 * qq + 2] = fmaf(h1, bb.z, acc[4 * qq + 2]);
        acc[4 * qq + 3] = fmaf(h1, bb.w, acc[4 * qq + 3]);
      }
    }
  }

  float mx = acc[0];
#pragma unroll
  for (int c = 1; c < K_C; ++c) mx = fmaxf(mx, acc[c]);
  float sum = 0.f;
#pragma unroll
  for (int c = 0; c < K_C; ++c) { acc[c] = __expf(acc[c] - mx); sum += acc[c]; }
  const float inv = 1.f / sum;
  float sq[K_C];
  if (node < n) {
#pragma unroll
    for (int c = 0; c < K_C; ++c) { acc[c] *= inv; sq[c] = acc[c] * acc[c]; }
    float4* o = (float4*)(sm_out + (size_t)node * K_C);
    o[0] = make_float4(acc[0], acc[1], acc[2], acc[3]);
    o[1] = make_float4(acc[4], acc[5], acc[6], acc[7]);
    o[2] = make_float4(acc[8], acc[9], acc[10], acc[11]);
    o[3] = make_float4(acc[12], acc[13], acc[14], acc[15]);
  } else {
#pragma unroll
    for (int c = 0; c < K_C; ++c) sq[c] = 0.f;
  }

#pragma unroll
  for (int c = 0; c < K_C; ++c) {
    float v = sq[c];
#pragma unroll
    for (int off2 = 32; off2; off2 >>= 1) v += __shfl_xor(v, off2);
    if (lane == 0) atomicAdd(&part[c], v);
  }
  __syncthreads();
  if (threadIdx.x < K_C) atomicAdd(&diag[threadIdx.x], part[threadIdx.x]);
  __syncthreads();
  __threadfence();
  if (threadIdx.x == 0)
    lastf = (atomicAdd(ctr, 1u) == (unsigned)(gridDim.x - 1)) ? 1 : 0;
  __syncthreads();
  if (lastf && threadIdx.x < 64) {
    const int c = threadIdx.x;
    float v = 0.f;
    if (c < K_C) v = sqrtf(atomicAdd(&diag[c], 0.f) + 1e-15f);
#pragma unroll
    for (int off2 = 8; off2; off2 >>= 1) v += __shfl_xor(v, off2, 16);
    if (c == 0) loss_out[0] = -v / sqrtf((float)N_NODES * (float)K_C);
  }
}

extern "C" void kernel_launch(void* const* d_in, const int* in_sizes, int n_in,
                              void* d_out, int out_size, void* d_ws, size_t ws_size,
                              hipStream_t stream) {
  const float* x  = (const float*)d_in[0];
  const int*   ei = (const int*)d_in[1];
  const float* ew = (const float*)d_in[2];
  const float* W1 = (const float*)d_in[3];
  const float* b1 = (const float*)d_in[4];
  const float* W2 = (const float*)d_in[5];
  const float* b2 = (const float*)d_in[6];
  const float* Wm = (const float*)d_in[7];
  const float* bm = (const float*)d_in[8];
  float* out = (float*)d_out;

  const int* srcv = ei;
  const int* dstv = ei + E_EDGES;

  char* ws = (char*)d_ws;
  float*        diag    = (float*)ws;                        // 16 f   (zeroed)
  unsigned int* ctr     = (unsigned int*)(ws + 64);          // 1 u32  (zeroed)
  int*          bcount  = (int*)(ws + 128);                  // NBUCK  (zeroed)
  int*          bcursor = (int*)(ws + 2048);                 // NBUCK  (zeroed)
  int*          bbase   = (int*)(ws + 4096);                 // NBUCK+1 (written by bin_pass)
  __half*       WT1     = (__half*)(ws + 8192);              // 16 KB
  __half*       WT2     = (__half*)(ws + 8192 + 16384);      // 32 KB
  int*          off     = (int*)(ws + 65536);                // N+1 ints
  unsigned int* csr     = (unsigned int*)(off + N_NODES + 64); // E uints (3.2 MB)
  int2*         inter   = (int2*)(csr + E_EDGES);            // E int2 (6.4 MB)
  char*         bufA    = (char*)(inter + E_EDGES);          // 12.8 MB region
  char*         bufB    = bufA + (size_t)N_NODES * H_F * 2;  // 12.8 MB region

  __half* xh    = (__half*)bufB;   // fp16 x [N][64]
  __half* aggxh = (__half*)bufA;   // fp16 A*x [N][64]
  __half* h1h   = (__half*)bufB;   // fp16 h1 [N][128] (overwrites xh)
  __half* t2h   = (__half*)bufA;   // fp16 t2 [N][128] (overwrites aggxh)
  __half* h2h   = (__half*)bufB;   // fp16 h2 [N][128] (overwrites h1h)

  // zero diag + ctr + bcount + bcursor in one shot
  hipMemsetAsync(ws, 0, 4096, stream);

  // fused prep + bucket hist
  prep_hist<<<PREP_B + NCHUNK, 256, 0, stream>>>(x, xh, W1, WT1, W2, WT2, dstv, bcount);

  // CSR build: bin (computes bbase in-block) -> sort(+off)
  bin_pass<<<NCHUNK, 256, 0, stream>>>(srcv, dstv, ew, bcount, bcursor, bbase, inter);
  sortoff_pass<<<NBUCK, 256, 0, stream>>>(inter, bbase, csr, off);

  // layer 1 (reordered): aggxh = A*xh; h1h = relu(aggxh @ W1 + b1)
  gather_x<<<N_NODES / 4, 256, 0, stream>>>(xh, off, csr, aggxh);
  gemm_mfma<IN_F, true><<<(N_NODES + 63) / 64, 256, 0, stream>>>(aggxh, WT1, b1, h1h, N_NODES);

  // layer 2: t2h = fp16(h1h @ W2); h2h = fp16(A * t2h)
  gemm_mfma<H_F, false><<<(N_NODES + 63) / 64, 256, 0, stream>>>(h1h, WT2, nullptr, t2h, N_NODES);
  gather_h<<<N_NODES / 4, 256, 0, stream>>>(t2h, off, csr, h2h);

  // head + fused loss
  head_kernel<<<(N_NODES + 255) / 256, 256, 0, stream>>>(
      h2h, b2, Wm, bm, out, diag, ctr, out + (size_t)N_NODES * K_C, N_NODES);
}

// Round 17
// 149.499 us; speedup vs baseline: 1.0493x; 1.0493x over previous
//
#include <hip/hip_runtime.h>
#include <hip/hip_fp16.h>
#include <math.h>

static constexpr int N_NODES = 50000;
static constexpr int E_EDGES = 800000;
static constexpr int IN_F = 64;
static constexpr int H_F = 128;
static constexpr int K_C = 16;
static constexpr int BUCK_SHIFT = 7;                          // 128 nodes/bucket
static constexpr int NBUCK = (N_NODES + 127) >> BUCK_SHIFT;   // 391
static constexpr int CHUNK_E = 4096;
static constexpr int NCHUNK = (E_EDGES + CHUNK_E - 1) / CHUNK_E; // 196
static constexpr int BUCK_CAP = 4096;
static constexpr int PREP_B = 3221;                           // prep blocks (824576 items)

typedef _Float16 h4 __attribute__((ext_vector_type(4)));
typedef _Float16 h8 __attribute__((ext_vector_type(8)));
typedef float f4 __attribute__((ext_vector_type(4)));

__device__ __forceinline__ void unpack(unsigned int e, int& s, float& w) {
  s = (int)(e & 0xffffu);
  w = __half2float(__ushort_as_half((unsigned short)(e >> 16)));
}

// ---------------- fused prep (f2h + W transposes) + bucket histogram ----------------
__global__ __launch_bounds__(256) void prep_hist(
    const float* __restrict__ x, __half* __restrict__ xh,
    const float* __restrict__ W1, __half* __restrict__ WT1,
    const float* __restrict__ W2, __half* __restrict__ WT2,
    const int* __restrict__ dst, int* __restrict__ bcount) {
  __shared__ int lh[NBUCK];
  if (blockIdx.x < PREP_B) {
    const int i = blockIdx.x * 256 + threadIdx.x;
    const int n4 = N_NODES * IN_F / 4;           // 800000
    if (i < n4) {
      float4 v = ((const float4*)x)[i];
      __half2* o = (__half2*)xh + (size_t)i * 2;
      o[0] = __floats2half2_rn(v.x, v.y);
      o[1] = __floats2half2_rn(v.z, v.w);
    }
    const int j = i - n4;
    if (j >= 0 && j < IN_F * 128) {
      const int k = j >> 7, col = j & 127;
      unsigned boff = (unsigned)((col * IN_F + k) * 2) ^ (unsigned)((col & 7) << 4);
      *(__half*)((char*)WT1 + boff) = __float2half_rn(W1[j]);
    }
    const int k2 = j - IN_F * 128;
    if (k2 >= 0 && k2 < H_F * 128) {
      const int k = k2 >> 7, col = k2 & 127;
      unsigned boff = (unsigned)((col * H_F + k) * 2) ^ (unsigned)((col & 7) << 4);
      *(__half*)((char*)WT2 + boff) = __float2half_rn(W2[k2]);
    }
  } else {
    const int cb = blockIdx.x - PREP_B;
    for (int i = threadIdx.x; i < NBUCK; i += 256) lh[i] = 0;
    __syncthreads();
    const int e0 = cb * CHUNK_E;
    const int cnt = min(CHUNK_E, E_EDGES - e0);
    for (int i = threadIdx.x; i < cnt; i += 256)
      atomicAdd(&lh[dst[e0 + i] >> BUCK_SHIFT], 1);
    __syncthreads();
    for (int i = threadIdx.x; i < NBUCK; i += 256)
      if (lh[i]) atomicAdd(&bcount[i], lh[i]);
  }
}

// ---------------- bucket scan: 1 wave, exclusive scan of 391 counts ----------------
__global__ __launch_bounds__(64) void bscan_kernel(
    const int* __restrict__ bcount, int* __restrict__ bbase, int* __restrict__ bcursor) {
  const int t = threadIdx.x;
  int carry = 0;
  for (int base = 0; base < NBUCK; base += 64) {
    const int idx = base + t;
    const int v = (idx < NBUCK) ? bcount[idx] : 0;
    int inc = v;
#pragma unroll
    for (int d = 1; d < 64; d <<= 1) {
      int u = __shfl_up(inc, d);
      if (t >= d) inc += u;
    }
    if (idx < NBUCK) {
      const int ex = carry + inc - v;
      bbase[idx] = ex;
      bcursor[idx] = ex;
    }
    carry += __shfl(inc, 63);
  }
  if (t == 0) bbase[NBUCK] = E_EDGES;
}

// ---------------- bin_pass: chunk -> bucket-sorted runs into inter ----------------
__global__ __launch_bounds__(256) void bin_pass(
    const int* __restrict__ src, const int* __restrict__ dst,
    const float* __restrict__ w, int* __restrict__ bcursor,
    int2* __restrict__ inter) {
  __shared__ int lhist[NBUCK];
  __shared__ int lstart[NBUCK];
  __shared__ int bbase_s[NBUCK];
  __shared__ int2 stage[CHUNK_E];  // 32 KB
  const int e0 = blockIdx.x * CHUNK_E;
  const int cnt = min(CHUNK_E, E_EDGES - e0);

  for (int i = threadIdx.x; i < NBUCK; i += 256) lhist[i] = 0;
  __syncthreads();
  for (int i = threadIdx.x; i < cnt; i += 256)
    atomicAdd(&lhist[dst[e0 + i] >> BUCK_SHIFT], 1);
  __syncthreads();

  if (threadIdx.x < 64) {
    const int lane = threadIdx.x;
    int carry = 0;
    for (int base = 0; base < NBUCK; base += 64) {
      const int idx = base + lane;
      const int v = (idx < NBUCK) ? lhist[idx] : 0;
      int inc = v;
#pragma unroll
      for (int d = 1; d < 64; d <<= 1) {
        int u = __shfl_up(inc, d);
        if (lane >= d) inc += u;
      }
      if (idx < NBUCK) lstart[idx] = carry + inc - v;
      carry += __shfl(inc, 63);
    }
  }
  __syncthreads();

  for (int b = threadIdx.x; b < NBUCK; b += 256) {
    const int c = lhist[b];
    bbase_s[b] = (c > 0) ? atomicAdd(&bcursor[b], c) : 0;
    lhist[b] = lstart[b];
  }
  __syncthreads();

  for (int i = threadIdx.x; i < cnt; i += 256) {
    const int d = dst[e0 + i];
    const int b = d >> BUCK_SHIFT;
    const int pos = atomicAdd(&lhist[b], 1);
    const unsigned short wb = __half_as_ushort(__float2half_rn(w[e0 + i]));
    stage[pos] = make_int2(src[e0 + i] | ((d & 127) << 16),
                           (int)wb | (b << 16));
  }
  __syncthreads();

  for (int i = threadIdx.x; i < cnt; i += 256) {
    const int2 en = stage[i];
    const int b = (en.y >> 16) & 0x1ff;
    inter[bbase_s[b] + (i - lstart[b])] = en;
  }
}

// ---------------- sortoff: per-bucket fine sort + write node-level off ----------------
__global__ __launch_bounds__(256) void sortoff_pass(
    const int2* __restrict__ inter, const int* __restrict__ bbase,
    unsigned int* __restrict__ csr, int* __restrict__ off) {
  __shared__ int lhist[128];
  __shared__ int lstart[128];
  __shared__ unsigned int outbuf[BUCK_CAP];  // 16 KB
  const int b = blockIdx.x;
  const int n0 = b << BUCK_SHIFT;
  const int r0 = bbase[b];
  const int r1 = bbase[b + 1];
  const int cnt = r1 - r0;

  if (threadIdx.x < 128) lhist[threadIdx.x] = 0;
  __syncthreads();
  for (int i = threadIdx.x; i < cnt; i += 256)
    atomicAdd(&lhist[(inter[r0 + i].x >> 16) & 127], 1);
  __syncthreads();

  if (threadIdx.x < 64) {
    const int lane = threadIdx.x;
    int carry = 0;
#pragma unroll
    for (int base = 0; base < 128; base += 64) {
      const int v = lhist[base + lane];
      int inc = v;
#pragma unroll
      for (int d = 1; d < 64; d <<= 1) {
        int u = __shfl_up(inc, d);
        if (lane >= d) inc += u;
      }
      lstart[base + lane] = carry + inc - v;
      carry += __shfl(inc, 63);
    }
  }
  __syncthreads();

  if (threadIdx.x < 128) {
    const int nn = n0 + threadIdx.x;
    if (nn < N_NODES) off[nn] = r0 + lstart[threadIdx.x];
    lhist[threadIdx.x] = lstart[threadIdx.x];
  }
  if (b == NBUCK - 1 && threadIdx.x == 0) off[N_NODES] = E_EDGES;
  __syncthreads();

  for (int i = threadIdx.x; i < cnt; i += 256) {
    const int2 en = inter[r0 + i];
    const int dlo = (en.x >> 16) & 127;
    const int pos = atomicAdd(&lhist[dlo], 1);
    outbuf[pos] = (unsigned int)(en.x & 0xffff) |
                  ((unsigned int)(en.y & 0xffff) << 16);
  }
  __syncthreads();
  for (int i = threadIdx.x; i < cnt; i += 256) csr[r0 + i] = outbuf[i];
}

// ---------------- gather_x: wave/node, 4 edge-slots x 16 feat-lanes; masked-16 tail ----------------
__global__ __launch_bounds__(256) void gather_x(
    const __half* __restrict__ t, const int* __restrict__ off,
    const unsigned int* __restrict__ csr, __half* __restrict__ outb) {
  const int node = blockIdx.x * 4 + (threadIdx.x >> 6);
  const int l = threadIdx.x & 63;
  const int g = l >> 4;                 // edge slot 0..3
  const int f0 = (l & 15) * 4;          // 4 feats per lane
  const int p0 = off[node], p1 = off[node + 1];
  f4 a0 = {0.f, 0.f, 0.f, 0.f}, a1 = {0.f, 0.f, 0.f, 0.f};
  int p = p0;
  for (; p + 16 <= p1; p += 16) {
    int s[4]; float w[4]; h4 v[4];
#pragma unroll
    for (int u = 0; u < 4; ++u) unpack(csr[p + 4 * u + g], s[u], w[u]);
#pragma unroll
    for (int u = 0; u < 4; ++u) v[u] = *(const h4*)(t + (size_t)s[u] * IN_F + f0);
#pragma unroll
    for (int u = 0; u < 4; ++u) {
      f4& a = (u & 1) ? a1 : a0;
      a.x = fmaf((float)v[u].x, w[u], a.x); a.y = fmaf((float)v[u].y, w[u], a.y);
      a.z = fmaf((float)v[u].z, w[u], a.z); a.w = fmaf((float)v[u].w, w[u], a.w);
    }
  }
  if (p < p1) {   // masked 16-wide tail
    int s[4]; float w[4]; h4 v[4];
#pragma unroll
    for (int u = 0; u < 4; ++u) {
      const int idx = p + 4 * u + g;
      unpack(csr[min(idx, p1 - 1)], s[u], w[u]);
      if (idx >= p1) w[u] = 0.f;
    }
#pragma unroll
    for (int u = 0; u < 4; ++u) v[u] = *(const h4*)(t + (size_t)s[u] * IN_F + f0);
#pragma unroll
    for (int u = 0; u < 4; ++u) {
      f4& a = (u & 1) ? a1 : a0;
      a.x = fmaf((float)v[u].x, w[u], a.x); a.y = fmaf((float)v[u].y, w[u], a.y);
      a.z = fmaf((float)v[u].z, w[u], a.z); a.w = fmaf((float)v[u].w, w[u], a.w);
    }
  }
  a0.x += a1.x; a0.y += a1.y; a0.z += a1.z; a0.w += a1.w;
  a0.x += __shfl_xor(a0.x, 16); a0.y += __shfl_xor(a0.y, 16);
  a0.z += __shfl_xor(a0.z, 16); a0.w += __shfl_xor(a0.w, 16);
  a0.x += __shfl_xor(a0.x, 32); a0.y += __shfl_xor(a0.y, 32);
  a0.z += __shfl_xor(a0.z, 32); a0.w += __shfl_xor(a0.w, 32);
  if (l < 16) {
    h4 o;
    o.x = (_Float16)a0.x; o.y = (_Float16)a0.y;
    o.z = (_Float16)a0.z; o.w = (_Float16)a0.w;
    *(h4*)(outb + (size_t)node * IN_F + f0) = o;
  }
}

// ---------------- MFMA dense transform ----------------
template<int K, bool BIAS_RELU>
__global__ __launch_bounds__(256) void gemm_mfma(
    const __half* __restrict__ A, const __half* __restrict__ WT,
    const float* __restrict__ bias, __half* __restrict__ out, int n) {
  __shared__ _Float16 Wl[128 * K];
  for (int t = threadIdx.x; t < 128 * K / 8; t += 256)
    ((uint4*)Wl)[t] = ((const uint4*)WT)[t];
  __syncthreads();

  const int wv = threadIdx.x >> 6;
  const int l = threadIdx.x & 63;
  const int row = l & 15, kg = l >> 4;
  const int r0 = blockIdx.x * 64 + wv * 16;
  const int ar = min(r0 + row, n - 1);

  h8 af[K / 32];
#pragma unroll
  for (int ks = 0; ks < K / 32; ++ks)
    af[ks] = *(const h8*)(A + (size_t)ar * K + ks * 32 + kg * 8);

  const unsigned swz = (unsigned)((row & 7) << 4);
#pragma unroll
  for (int c = 0; c < 8; ++c) {
    const int col = c * 16 + row;
    f4 acc = {0.f, 0.f, 0.f, 0.f};
#pragma unroll
    for (int ks = 0; ks < K / 32; ++ks) {
      const unsigned boff = ((unsigned)((col * K + ks * 32 + kg * 8) * 2)) ^ swz;
      const h8 bf = *(const h8*)((const char*)Wl + boff);
      acc = __builtin_amdgcn_mfma_f32_16x16x32_f16(af[ks], bf, acc, 0, 0, 0);
    }
    const float bb = BIAS_RELU ? bias[col] : 0.f;
#pragma unroll
    for (int q = 0; q < 4; ++q) {
      const int rr = r0 + kg * 4 + q;
      if (rr < n) {
        float v = acc[q];
        if (BIAS_RELU) v = fmaxf(v + bb, 0.f);
        out[(size_t)rr * H_F + col] = __float2half_rn(v);
      }
    }
  }
}

// ---------------- gather_h: wave/node, full-row lanes, 16-wide + masked-16 tail ----------------
__global__ __launch_bounds__(256) void gather_h(
    const __half* __restrict__ t, const int* __restrict__ off,
    const unsigned int* __restrict__ csr, __half* __restrict__ outb) {
  const int node = blockIdx.x * 4 + (threadIdx.x >> 6);
  const int lane = threadIdx.x & 63;
  const __half2* __restrict__ tb = (const __half2*)t;
  const int p0 = off[node], p1 = off[node + 1];
  float2 a[4];
#pragma unroll
  for (int i = 0; i < 4; ++i) a[i] = make_float2(0.f, 0.f);
  int p = p0;
  for (; p + 16 <= p1; p += 16) {
    int s[16]; float w[16]; __half2 hv[16];
#pragma unroll
    for (int i = 0; i < 16; ++i) unpack(csr[p + i], s[i], w[i]);
#pragma unroll
    for (int i = 0; i < 16; ++i) hv[i] = tb[(size_t)s[i] * 64 + lane];
#pragma unroll
    for (int i = 0; i < 16; ++i) {
      const float2 f = __half22float2(hv[i]);
      a[i & 3].x = fmaf(f.x, w[i], a[i & 3].x);
      a[i & 3].y = fmaf(f.y, w[i], a[i & 3].y);
    }
  }
  if (p < p1) {   // masked 16-wide tail
    int s[16]; float w[16]; __half2 hv[16];
#pragma unroll
    for (int i = 0; i < 16; ++i) {
      unpack(csr[min(p + i, p1 - 1)], s[i], w[i]);
      if (p + i >= p1) w[i] = 0.f;
    }
#pragma unroll
    for (int i = 0; i < 16; ++i) hv[i] = tb[(size_t)s[i] * 64 + lane];
#pragma unroll
    for (int i = 0; i < 16; ++i) {
      const float2 f = __half22float2(hv[i]);
      a[i & 3].x = fmaf(f.x, w[i], a[i & 3].x);
      a[i & 3].y = fmaf(f.y, w[i], a[i & 3].y);
    }
  }
  const float2 s2 = make_float2((a[0].x + a[1].x) + (a[2].x + a[3].x),
                                (a[0].y + a[1].y) + (a[2].y + a[3].y));
  ((__half2*)outb)[(size_t)node * 64 + lane] = __float22half2_rn(s2);
}

// ---------------- head: one node per thread, 16 independent accumulators ----------------
__global__ __launch_bounds__(256) void head_kernel(
    const __half* __restrict__ h2raw, const float* __restrict__ b2,
    const float* __restrict__ Wm, const float* __restrict__ bm,
    float* __restrict__ sm_out, float* __restrict__ diag, int n) {
  __shared__ float Wl[H_F * K_C];   // 8 KB, [k][c]
  __shared__ float b2l[H_F];
  __shared__ float part[K_C];
  for (int t = threadIdx.x; t < H_F * K_C; t += 256) Wl[t] = Wm[t];
  if (threadIdx.x < H_F) b2l[threadIdx.x] = b2[threadIdx.x];
  if (threadIdx.x < K_C) part[threadIdx.x] = 0.f;
  __syncthreads();

  const int node = blockIdx.x * 256 + threadIdx.x;
  const int lane = threadIdx.x & 63;
  float acc[K_C];
#pragma unroll
  for (int c = 0; c < K_C; ++c) acc[c] = bm[c];

  if (node < n) {
    const __half2* __restrict__ hrow = (const __half2*)(h2raw + (size_t)node * H_F);
#pragma unroll 4
    for (int k2 = 0; k2 < H_F / 2; ++k2) {
      const float2 hv = __half22float2(hrow[k2]);
      const float h0 = fmaxf(hv.x + b2l[2 * k2], 0.f);
      const float h1 = fmaxf(hv.y + b2l[2 * k2 + 1], 0.f);
      const float4* __restrict__ w0 = (const float4*)(Wl + (2 * k2) * K_C);      // uniform
      const float4* __restrict__ w1 = (const float4*)(Wl + (2 * k2 + 1) * K_C);  // uniform
#pragma unroll
      for (int q = 0; q < 4; ++q) {
        const float4 aa = w0[q], bb = w1[q];
        acc[4 * q + 0] = fmaf(h0, aa.x, acc[4 * q + 0]);
        acc[4 * q + 1] = fmaf(h0, aa.y, acc[4 * q + 1]);
        acc[4 * q + 2] = fmaf(h0, aa.z, acc[4 * q + 2]);
        acc[4 * q + 3] = fmaf(h0, aa.w, acc[4 * q + 3]);
        acc[4 * q + 0] = fmaf(h1, bb.x, acc[4 * q + 0]);
        acc[4 * q + 1] = fmaf(h1, bb.y, acc[4 * q + 1]);
        acc[4 * q + 2] = fmaf(h1, bb.z, acc[4 * q + 2]);
        acc[4 * q + 3] = fmaf(h1, bb.w, acc[4 * q + 3]);
      }
    }
  }

  float mx = acc[0];
#pragma unroll
  for (int c = 1; c < K_C; ++c) mx = fmaxf(mx, acc[c]);
  float sum = 0.f;
#pragma unroll
  for (int c = 0; c < K_C; ++c) { acc[c] = __expf(acc[c] - mx); sum += acc[c]; }
  const float inv = 1.f / sum;
  float sq[K_C];
  if (node < n) {
#pragma unroll
    for (int c = 0; c < K_C; ++c) { acc[c] *= inv; sq[c] = acc[c] * acc[c]; }
    float4* o = (float4*)(sm_out + (size_t)node * K_C);
    o[0] = make_float4(acc[0], acc[1], acc[2], acc[3]);
    o[1] = make_float4(acc[4], acc[5], acc[6], acc[7]);
    o[2] = make_float4(acc[8], acc[9], acc[10], acc[11]);
    o[3] = make_float4(acc[12], acc[13], acc[14], acc[15]);
  } else {
#pragma unroll
    for (int c = 0; c < K_C; ++c) sq[c] = 0.f;
  }

#pragma unroll
  for (int c = 0; c < K_C; ++c) {
    float v = sq[c];
#pragma unroll
    for (int off2 = 32; off2; off2 >>= 1) v += __shfl_xor(v, off2);
    if (lane == 0) atomicAdd(&part[c], v);
  }
  __syncthreads();
  if (threadIdx.x < K_C) atomicAdd(&diag[threadIdx.x], part[threadIdx.x]);
}

__global__ void loss_kernel(const float* __restrict__ diag, float* __restrict__ out) {
  int c = threadIdx.x;
  float v = (c < K_C) ? sqrtf(diag[c] + 1e-15f) : 0.f;
#pragma unroll
  for (int off2 = 8; off2; off2 >>= 1) v += __shfl_xor(v, off2, 16);
  if (c == 0) out[0] = -v / sqrtf((float)N_NODES * (float)K_C);
}

extern "C" void kernel_launch(void* const* d_in, const int* in_sizes, int n_in,
                              void* d_out, int out_size, void* d_ws, size_t ws_size,
                              hipStream_t stream) {
  const float* x  = (const float*)d_in[0];
  const int*   ei = (const int*)d_in[1];
  const float* ew = (const float*)d_in[2];
  const float* W1 = (const float*)d_in[3];
  const float* b1 = (const float*)d_in[4];
  const float* W2 = (const float*)d_in[5];
  const float* b2 = (const float*)d_in[6];
  const float* Wm = (const float*)d_in[7];
  const float* bm = (const float*)d_in[8];
  float* out = (float*)d_out;

  const int* srcv = ei;
  const int* dstv = ei + E_EDGES;

  char* ws = (char*)d_ws;
  float*        diag    = (float*)ws;                        // 16 f   (zeroed)
  int*          bcount  = (int*)(ws + 128);                  // NBUCK  (zeroed)
  int*          bcursor = (int*)(ws + 2048);                 // NBUCK  (seeded by bscan)
  int*          bbase   = (int*)(ws + 4096);                 // NBUCK+1 (written by bscan)
  __half*       WT1     = (__half*)(ws + 8192);              // 16 KB
  __half*       WT2     = (__half*)(ws + 8192 + 16384);      // 32 KB
  int*          off     = (int*)(ws + 65536);                // N+1 ints
  unsigned int* csr     = (unsigned int*)(off + N_NODES + 64); // E uints (3.2 MB)
  int2*         inter   = (int2*)(csr + E_EDGES);            // E int2 (6.4 MB)
  char*         bufA    = (char*)(inter + E_EDGES);          // 12.8 MB region
  char*         bufB    = bufA + (size_t)N_NODES * H_F * 2;  // 12.8 MB region

  __half* xh    = (__half*)bufB;   // fp16 x [N][64]
  __half* aggxh = (__half*)bufA;   // fp16 A*x [N][64]
  __half* h1h   = (__half*)bufB;   // fp16 h1 [N][128] (overwrites xh)
  __half* t2h   = (__half*)bufA;   // fp16 t2 [N][128] (overwrites aggxh)
  __half* h2h   = (__half*)bufB;   // fp16 h2 [N][128] (overwrites h1h)

  // zero diag + bcount in one shot
  hipMemsetAsync(ws, 0, 2048, stream);

  // fused prep + bucket hist
  prep_hist<<<PREP_B + NCHUNK, 256, 0, stream>>>(x, xh, W1, WT1, W2, WT2, dstv, bcount);

  // CSR build: bucket scan -> bin -> sort(+off)
  bscan_kernel<<<1, 64, 0, stream>>>(bcount, bbase, bcursor);
  bin_pass<<<NCHUNK, 256, 0, stream>>>(srcv, dstv, ew, bcursor, inter);
  sortoff_pass<<<NBUCK, 256, 0, stream>>>(inter, bbase, csr, off);

  // layer 1 (reordered): aggxh = A*xh; h1h = relu(aggxh @ W1 + b1)
  gather_x<<<N_NODES / 4, 256, 0, stream>>>(xh, off, csr, aggxh);
  gemm_mfma<IN_F, true><<<(N_NODES + 63) / 64, 256, 0, stream>>>(aggxh, WT1, b1, h1h, N_NODES);

  // layer 2: t2h = fp16(h1h @ W2); h2h = fp16(A * t2h)
  gemm_mfma<H_F, false><<<(N_NODES + 63) / 64, 256, 0, stream>>>(h1h, WT2, nullptr, t2h, N_NODES);
  gather_h<<<N_NODES / 4, 256, 0, stream>>>(t2h, off, csr, h2h);

  // head + loss
  head_kernel<<<(N_NODES + 255) / 256, 256, 0, stream>>>(h2h, b2, Wm, bm, out, diag, N_NODES);
  loss_kernel<<<1, 64, 0, stream>>>(diag, out + (size_t)N_NODES * K_C);
}